// Round 1
// baseline (106.373 us; speedup 1.0000x reference)
//
#include <hip/hip_runtime.h>

#define BS_TOTAL 256   // B*S
#define NP 64          // prototypes
#define NV 2562        // vertices
#define GROUP 8        // bs per main-kernel block
#define TB 128         // threads per main-kernel block (one v each)
#define RWS_STRIDE 12  // 9 used + 3 pad, keeps 16B alignment

// ---------------- prep: per (bs,p) scaled rotation matrix + reductions ------
__global__ __launch_bounds__(64) void prep_kernel(
    const float* __restrict__ scales,      // [256]
    const float* __restrict__ transforms,  // [256][64][6]
    const float* __restrict__ weights,     // [256][64]
    float* __restrict__ rws,               // [256][64][12]
    float* __restrict__ aux)               // [256][12]  (Rsum[9], trans[3])
{
    const int bs = blockIdx.x;
    const int p  = threadIdx.x;

    const float* t = transforms + ((size_t)bs * NP + p) * 6;
    const float tx = t[0], ty = t[1], tz = t[2];
    const float ax = t[3], ay = t[4], az = t[5];
    const float w  = weights[bs * NP + p];
    const float sc = scales[bs];
    const float ws = w * sc;

    float sx, cx, sy, cy, sz, cz;
    sincosf(ax, &sx, &cx);
    sincosf(ay, &sy, &cy);
    sincosf(az, &sz, &cz);

    // R = Rx(ax) @ Ry(ay) @ Rz(az), row-major
    float v12[12];
    v12[0] = (cy * cz) * ws;
    v12[1] = (-cy * sz) * ws;
    v12[2] = (sy) * ws;
    v12[3] = (cx * sz + sx * sy * cz) * ws;
    v12[4] = (cx * cz - sx * sy * sz) * ws;
    v12[5] = (-sx * cy) * ws;
    v12[6] = (sx * sz - cx * sy * cz) * ws;
    v12[7] = (sx * cz + cx * sy * sz) * ws;
    v12[8] = (cx * cy) * ws;
    v12[9]  = w * tx;
    v12[10] = w * ty;
    v12[11] = w * tz;

    float4* dst = (float4*)(rws + ((size_t)bs * NP + p) * RWS_STRIDE);
    dst[0] = make_float4(v12[0], v12[1], v12[2],  v12[3]);
    dst[1] = make_float4(v12[4], v12[5], v12[6],  v12[7]);
    dst[2] = make_float4(v12[8], v12[9], v12[10], v12[11]);

    // wave(=block) reduction over p: Rsum (k=0..8), trans (k=9..11)
    float red[12];
#pragma unroll
    for (int k = 0; k < 12; ++k) red[k] = v12[k];
#pragma unroll
    for (int m = 1; m < 64; m <<= 1) {
#pragma unroll
        for (int k = 0; k < 12; ++k) red[k] += __shfl_xor(red[k], m);
    }
    if (p == 0) {
        float4* adst = (float4*)(aux + (size_t)bs * 12);
        adst[0] = make_float4(red[0], red[1], red[2],  red[3]);
        adst[1] = make_float4(red[4], red[5], red[6],  red[7]);
        adst[2] = make_float4(red[8], red[9], red[10], red[11]);
    }
}

// ---------------- main: out[bs,v,i] = Rsum.bv + sum_p Rws.off + trans -------
__global__ __launch_bounds__(TB) void mesh_kernel(
    const float* __restrict__ rws,      // [256][64][12]
    const float* __restrict__ aux,      // [256][12]
    const float* __restrict__ offsets,  // [64][2562][3]
    const float* __restrict__ bverts,   // [2562][3]
    float* __restrict__ out)            // [256][2562][3]
{
    const int v   = blockIdx.x * TB + threadIdx.x;
    const int vc  = v < NV ? v : NV - 1;   // clamp loads, guard only the store
    const int bs0 = blockIdx.y * GROUP;

    const float bx = bverts[vc * 3 + 0];
    const float by = bverts[vc * 3 + 1];
    const float bz = bverts[vc * 3 + 2];

    float acc[GROUP][3];
#pragma unroll
    for (int g = 0; g < GROUP; ++g) {
        const float* a = aux + (size_t)(bs0 + g) * 12;   // wave-uniform
        acc[g][0] = a[0] * bx + a[1] * by + a[2] * bz + a[9];
        acc[g][1] = a[3] * bx + a[4] * by + a[5] * bz + a[10];
        acc[g][2] = a[6] * bx + a[7] * by + a[8] * bz + a[11];
    }

    const float* rbase = rws + (size_t)bs0 * NP * RWS_STRIDE;
    for (int p = 0; p < NP; ++p) {
        const float* o = offsets + ((size_t)p * NV + vc) * 3;
        const float ox = o[0], oy = o[1], oz = o[2];
#pragma unroll
        for (int g = 0; g < GROUP; ++g) {
            const float* r = rbase + ((size_t)g * NP + p) * RWS_STRIDE;  // wave-uniform
            acc[g][0] += r[0] * ox + r[1] * oy + r[2] * oz;
            acc[g][1] += r[3] * ox + r[4] * oy + r[5] * oz;
            acc[g][2] += r[6] * ox + r[7] * oy + r[8] * oz;
        }
    }

    if (v < NV) {
#pragma unroll
        for (int g = 0; g < GROUP; ++g) {
            float* po = out + ((size_t)(bs0 + g) * NV + v) * 3;
            po[0] = acc[g][0];
            po[1] = acc[g][1];
            po[2] = acc[g][2];
        }
    }
}

extern "C" void kernel_launch(void* const* d_in, const int* in_sizes, int n_in,
                              void* d_out, int out_size, void* d_ws, size_t ws_size,
                              hipStream_t stream) {
    const float* scales     = (const float*)d_in[0];
    const float* transforms = (const float*)d_in[1];
    const float* weights    = (const float*)d_in[2];
    const float* offsets    = (const float*)d_in[3];
    const float* bverts     = (const float*)d_in[4];
    float* out = (float*)d_out;

    float* rws = (float*)d_ws;                           // 256*64*12 floats
    float* aux = rws + (size_t)BS_TOTAL * NP * RWS_STRIDE; // 256*12 floats

    prep_kernel<<<dim3(BS_TOTAL), dim3(64), 0, stream>>>(scales, transforms, weights, rws, aux);

    dim3 grid((NV + TB - 1) / TB, BS_TOTAL / GROUP);     // (21, 32) = 672 blocks
    mesh_kernel<<<grid, dim3(TB), 0, stream>>>(rws, aux, offsets, bverts, out);
}